// Round 5
// baseline (485.958 us; speedup 1.0000x reference)
//
#include <hip/hip_runtime.h>
#include <hip/hip_cooperative_groups.h>
#include <cstdint>
#include <cstddef>

// Exact radix select on order-transformed x bits among t<0 entries
// (t = -1 exactly => negative_loss = softplus(x), strictly increasing in x).
//
// R9: single cooperative kernel (R8's 7-dispatch chain fused; measured ledger
// shows ~10-12 us fixed cost PER DISPATCH on this harness — the chain's work
// is only ~45-50 us but R0/R8 both sit ~130 us above their work estimate).
// Phases (grid.sync between):
//   P0: zero hrep + h21 in-kernel (kills the memset dispatch)
//   P1: stream x,t (82 MB): 2048-bin LDS hist (bits31:21) -> 8-way replicated
//       global hist; compact negatives' u into per-wave cand1 segments
//       (register cursor + shfl scan, no atomics); 2-bit class map.
//   P2: every block redundantly: rank-select 11-bit prefix1 from hrep (64 KB,
//       L2/L3-hot broadcast read; no SelState round-trip).
//   P3: each wave re-reads its OWN cand1 segment (wcur still in a register —
//       wvcnt array eliminated), filters prefix1, scatter-atomics into
//       2^21-bin h21 (scattered lines -> no ping-pong; proven R0/R8).
//   P4: per-chunk sums of h21 (1024 chunks, grid-stride).
//   P5: every block redundantly: pick chunk then bin -> u_kth + precise thr.
//   P6: k_final: x + cmap (cmap is block-local produce/consume), fast
//       __expf/__logf values, bit-exact mask, precise re-check only in a
//       256-ulp guard band.
// Legacy R8 multi-kernel chain kept below as a fallback if cooperative launch
// is rejected (g_coop latch).
//
// Atomic-design ledger (measured):
//   R5: 140k device atomics on 4 KB hist  -> 64-line ping-pong, 47 us. BAD.
//   R6: single block over scattered segs  -> latency chain, 76 us. BAD.
//   R7: single block streaming 2x ~1 MB   -> single-CU BW bound. MEH.
//   R8: scattered 2^21 scatter + replicated hist merge. GOOD (167 us).
//   R9: R8 dataflow, 1 dispatch.

struct SelState {
    uint32_t prefix1;
    uint32_t k1rem;
    uint32_t prefix2;
    uint32_t k2rem;
    uint32_t u_kth;
    float    thr_nl;
    uint32_t done;
};

#define GUARD 256u
#define HREP 8

namespace cg = cooperative_groups;

__device__ __forceinline__ uint32_t xform(uint32_t b) {
    return ((int32_t)b < 0) ? ~b : (b | 0x80000000u);
}
__device__ __forceinline__ float unxform(uint32_t u) {
    uint32_t b = (u & 0x80000000u) ? (u ^ 0x80000000u) : ~u;
    return __uint_as_float(b);
}
__device__ __forceinline__ float neg_loss_precise(float x, float t) {
#pragma clang fp contract(off)
    return (fmaxf(-x, 0.0f) - x * t) + log1pf(expf(-fabsf(x)));
}

// wave-wide inclusive scan -> exclusive offset + total (64 lanes)
__device__ __forceinline__ void wscan(uint32_t m, int lane, uint32_t& excl, uint32_t& tot) {
    uint32_t inc = m;
#pragma unroll
    for (int d = 1; d < 64; d <<= 1) {
        uint32_t v = __shfl_up(inc, (unsigned)d, 64);
        if (lane >= d) inc += v;
    }
    excl = inc - m;
    tot = __shfl(inc, 63, 64);
}

__device__ __forceinline__ uint32_t quad_u_cls(uint32_t* my, float4 xv, float4 tv,
        uint32_t& u0, uint32_t& u1, uint32_t& u2, uint32_t& u3) {
    u0 = (tv.x < 0.0f) ? xform(__float_as_uint(xv.x)) : 0u;
    u1 = (tv.y < 0.0f) ? xform(__float_as_uint(xv.y)) : 0u;
    u2 = (tv.z < 0.0f) ? xform(__float_as_uint(xv.z)) : 0u;
    u3 = (tv.w < 0.0f) ? xform(__float_as_uint(xv.w)) : 0u;
    uint32_t cls = ((tv.x > 0.0f) ? 1u : ((tv.x < 0.0f) ? 2u : 0u))
                 | (((tv.y > 0.0f) ? 1u : ((tv.y < 0.0f) ? 2u : 0u)) << 2)
                 | (((tv.z > 0.0f) ? 1u : ((tv.z < 0.0f) ? 2u : 0u)) << 4)
                 | (((tv.w > 0.0f) ? 1u : ((tv.w < 0.0f) ? 2u : 0u)) << 6);
    if (u0) atomicAdd(&my[u0 >> 21], 1u);
    if (u1) atomicAdd(&my[u1 >> 21], 1u);
    if (u2) atomicAdd(&my[u2 >> 21], 1u);
    if (u3) atomicAdd(&my[u3 >> 21], 1u);
    return cls;
}

// ---------------- final-pass value helpers ----------------
__device__ __forceinline__ float fin1c(float xx, uint32_t cls, uint32_t ukth, float thr) {
    float lp = __logf(1.0f + __expf(-fabsf(xx)));
    float v = 0.0f;
    if (cls == 1u) {
        v = (fmaxf(xx, 0.0f) - xx) + lp;
    } else if (cls == 2u) {
        uint32_t u = xform(__float_as_uint(xx));
        bool keep = u < ukth;
        if (keep && (ukth - u) < GUARD)
            keep = neg_loss_precise(xx, -1.0f) < thr;
        if (keep) v = (fmaxf(-xx, 0.0f) + xx) + lp;
    }
    return v;
}
__device__ __forceinline__ float4 fin_quadc(float4 xv, uint32_t cb, uint32_t ukth, float thr) {
    float4 r;
    r.x = fin1c(xv.x, cb & 3u, ukth, thr);
    r.y = fin1c(xv.y, (cb >> 2) & 3u, ukth, thr);
    r.z = fin1c(xv.z, (cb >> 4) & 3u, ukth, thr);
    r.w = fin1c(xv.w, (cb >> 6) & 3u, ukth, thr);
    return r;
}
__device__ __forceinline__ float fin1t(float xx, float tt, uint32_t ukth, float thr) {
    float lp = __logf(1.0f + __expf(-fabsf(xx)));
    float v = 0.0f;
    if (tt > 0.0f) {
        v = fmaxf(xx, 0.0f) - xx * tt + lp;
    } else if (tt < 0.0f) {
        uint32_t u = xform(__float_as_uint(xx));
        bool keep = u < ukth;
        if (keep && (ukth - u) < GUARD)
            keep = neg_loss_precise(xx, tt) < thr;
        if (keep) v = fmaxf(-xx, 0.0f) - xx * tt + lp;
    }
    return v;
}

// =====================================================================
// R9 fused cooperative kernel
// =====================================================================
__global__ __launch_bounds__(256, 4) void fused(
        const float* __restrict__ x, const float* __restrict__ t,
        const int* __restrict__ kptr,
        uint32_t* __restrict__ hrep, uint32_t* __restrict__ h21,
        uint32_t* __restrict__ csums, uint32_t* __restrict__ cand1,
        uint8_t* __restrict__ cmap, float* __restrict__ out,
        int n, int segw) {
    cg::grid_group gg = cg::this_grid();
    __shared__ uint32_t lh[2 * 2049];   // P1 hist (2-way replicated, +1 pad)
    __shared__ uint32_t part[256];
    __shared__ uint32_t bc[8];          // block broadcast slots

    const int tid  = threadIdx.x;
    const int bid  = blockIdx.x;
    const int nblk = gridDim.x;
    const int S    = nblk * 256;
    const int gtid = bid * 256 + tid;
    const int n4   = n >> 2;
    const int lane = tid & 63;
    const int wid  = tid >> 6;

    // ---- P0: zero hrep + h21 (replaces the memset dispatch) ----
    for (int j = gtid; j < HREP * 2048; j += S) hrep[j] = 0u;
    {
        uint4* h4 = (uint4*)h21;
        uint4 z; z.x = 0u; z.y = 0u; z.z = 0u; z.w = 0u;
        for (int j = gtid; j < (1 << 19); j += S) h4[j] = z;
    }
    gg.sync();

    // ---- P1: stream x,t -> LDS hist + per-wave compaction + class map ----
    for (int j = tid; j < 2 * 2049; j += 256) lh[j] = 0;
    __syncthreads();
    uint32_t* my = &lh[(tid & 1) * 2049];

    const float4* x4 = (const float4*)x;
    const float4* t4 = (const float4*)t;
    uint32_t* wseg = cand1 + (size_t)(bid * 4 + wid) * (size_t)segw;
    uint32_t wcur = 0;   // wave-uniform cursor; stays live into P3

    int M4 = 0;
    {
        long rem = (long)n4 - 1 - (long)(bid * 256 + 255);
        if (rem >= 0) {
            long T = rem / S;
            if (T >= 3) M4 = (int)((T - 3) / 4 + 1);
        }
    }
    int i = bid * 256 + tid;

    for (int b = 0; b < M4; ++b, i += 4 * S) {   // 8 independent 16B loads in flight
        float4 xa = x4[i], xb = x4[i + S], xc = x4[i + 2 * S], xd = x4[i + 3 * S];
        float4 ta = t4[i], tb = t4[i + S], tc = t4[i + 2 * S], td = t4[i + 3 * S];
        uint32_t u0, u1, u2, u3, u4_, u5, u6, u7, u8, u9, uA, uB, uC, uD, uE, uF;
        uint32_t ca = quad_u_cls(my, xa, ta, u0, u1, u2, u3);
        uint32_t cb = quad_u_cls(my, xb, tb, u4_, u5, u6, u7);
        uint32_t cc = quad_u_cls(my, xc, tc, u8, u9, uA, uB);
        uint32_t cd = quad_u_cls(my, xd, td, uC, uD, uE, uF);
        cmap[i]         = (uint8_t)ca;
        cmap[i + S]     = (uint8_t)cb;
        cmap[i + 2 * S] = (uint8_t)cc;
        cmap[i + 3 * S] = (uint8_t)cd;
        uint32_t m = (u0 != 0) + (u1 != 0) + (u2 != 0) + (u3 != 0)
                   + (u4_ != 0) + (u5 != 0) + (u6 != 0) + (u7 != 0)
                   + (u8 != 0) + (u9 != 0) + (uA != 0) + (uB != 0)
                   + (uC != 0) + (uD != 0) + (uE != 0) + (uF != 0);
        uint32_t excl, tot;
        wscan(m, lane, excl, tot);
        uint32_t p = wcur + excl;
        if (u0)  wseg[p++] = u0;
        if (u1)  wseg[p++] = u1;
        if (u2)  wseg[p++] = u2;
        if (u3)  wseg[p++] = u3;
        if (u4_) wseg[p++] = u4_;
        if (u5)  wseg[p++] = u5;
        if (u6)  wseg[p++] = u6;
        if (u7)  wseg[p++] = u7;
        if (u8)  wseg[p++] = u8;
        if (u9)  wseg[p++] = u9;
        if (uA)  wseg[p++] = uA;
        if (uB)  wseg[p++] = uB;
        if (uC)  wseg[p++] = uC;
        if (uD)  wseg[p++] = uD;
        if (uE)  wseg[p++] = uE;
        if (uF)  wseg[p++] = uF;
        wcur += tot;
    }

    for (; __any(i < n4); i += S) {
        const bool act = i < n4;
        float4 xa = act ? x4[i] : make_float4(0.f, 0.f, 0.f, 0.f);
        float4 ta = act ? t4[i] : make_float4(0.f, 0.f, 0.f, 0.f);
        uint32_t u0, u1, u2, u3;
        uint32_t ca = quad_u_cls(my, xa, ta, u0, u1, u2, u3);
        if (act) cmap[i] = (uint8_t)ca;
        uint32_t m = (u0 != 0) + (u1 != 0) + (u2 != 0) + (u3 != 0);
        uint32_t excl, tot;
        wscan(m, lane, excl, tot);
        uint32_t p = wcur + excl;
        if (u0) wseg[p++] = u0;
        if (u1) wseg[p++] = u1;
        if (u2) wseg[p++] = u2;
        if (u3) wseg[p++] = u3;
        wcur += tot;
    }

    if (bid == 0) {   // n % 4 tail
        int j = (n4 << 2) + tid;
        const bool act = j < n;
        float xx = act ? x[j] : 0.0f;
        float tt = act ? t[j] : 0.0f;
        uint32_t u0 = (tt < 0.0f) ? xform(__float_as_uint(xx)) : 0u;
        if (u0) atomicAdd(&my[u0 >> 21], 1u);
        uint32_t excl, tot;
        wscan(u0 != 0 ? 1u : 0u, lane, excl, tot);
        if (u0) wseg[wcur + excl] = u0;
        wcur += tot;
    }

    __syncthreads();
    {
        uint32_t* hmine = hrep + (size_t)(bid & (HREP - 1)) * 2048;
        for (int b2 = tid; b2 < 2048; b2 += 256) {
            uint32_t c = lh[b2] + lh[2049 + b2];
            if (c) atomicAdd(&hmine[b2], c);
        }
    }
    gg.sync();

    // ---- P2: every block redundantly: pick 11-bit prefix1 ----
    uint32_t mode, prefix1 = 0, k1rem = 0;
    {
        uint32_t cnt8[8];
        uint32_t lsum = 0;
#pragma unroll
        for (int j = 0; j < 8; ++j) {
            uint32_t c = 0;
#pragma unroll
            for (int r = 0; r < HREP; ++r) c += hrep[r * 2048 + tid * 8 + j];
            cnt8[j] = c;
            lsum += c;
        }
        part[tid] = lsum;
        __syncthreads();
        for (int off = 1; off < 256; off <<= 1) {   // inclusive suffix sum
            uint32_t add = (tid + off < 256) ? part[tid + off] : 0u;
            __syncthreads();
            part[tid] += add;
            __syncthreads();
        }
        const uint32_t total = part[0];
        int kk = *kptr;
        uint32_t k = (kk > 0) ? (uint32_t)kk : 0u;
        if (k == 0u) {          // keep all negatives
            if (tid == 0) { bc[0] = 1u; bc[3] = 0xFFFFFFFFu; bc[4] = 0x7F800000u; }
        } else if (k > total) { // drop all negatives
            if (tid == 0) { bc[0] = 1u; bc[3] = 0u; bc[4] = 0u; }
        } else {
            if (tid == 0) bc[0] = 0u;
            uint32_t A = (tid < 255) ? part[tid + 1] : 0u;
#pragma unroll
            for (int j = 7; j >= 0; --j) {
                uint32_t c = cnt8[j];
                if (A < k && k <= A + c) { bc[1] = (uint32_t)(tid * 8 + j); bc[2] = k - A; }
                A += c;
            }
        }
        __syncthreads();
        mode = bc[0];
        prefix1 = bc[1];
        k1rem = bc[2];
    }

    // ---- P3: scatter own candidates (wcur lives in a register) ----
    if (mode == 0u) {
        const uint32_t cnt = wcur;
        const uint4* b4 = (const uint4*)wseg;
        const uint32_t iters = (cnt + 255u) >> 8;   // wave-uniform
        for (uint32_t it = 0; it < iters; ++it) {
            const uint32_t e0 = it * 256u + (uint32_t)lane * 4u;
            uint4 v = b4[it * 64u + (uint32_t)lane];
            if (e0 + 0u < cnt && (v.x >> 21) == prefix1) atomicAdd(&h21[v.x & 0x1FFFFFu], 1u);
            if (e0 + 1u < cnt && (v.y >> 21) == prefix1) atomicAdd(&h21[v.y & 0x1FFFFFu], 1u);
            if (e0 + 2u < cnt && (v.z >> 21) == prefix1) atomicAdd(&h21[v.z & 0x1FFFFFu], 1u);
            if (e0 + 3u < cnt && (v.w >> 21) == prefix1) atomicAdd(&h21[v.w & 0x1FFFFFu], 1u);
        }
    }
    gg.sync();

    // ---- P4: per-chunk sums of h21 (1024 chunks x 2048 bins) ----
    if (mode == 0u) {
        for (int c = bid; c < 1024; c += nblk) {
            const uint4* b4c = (const uint4*)(h21 + (size_t)c * 2048);
            uint32_t s = 0;
            for (int j = tid; j < 512; j += 256) {
                uint4 v = b4c[j];
                s += v.x + v.y + v.z + v.w;
            }
            part[tid] = s;
            __syncthreads();
            for (int off = 128; off > 0; off >>= 1) {
                if (tid < off) part[tid] += part[tid + off];
                __syncthreads();
            }
            if (tid == 0) csums[c] = part[0];
            __syncthreads();
        }
    }
    gg.sync();

    // ---- P5: every block redundantly: pick chunk then bin -> u_kth, thr ----
    if (mode == 0u) {
        uint32_t c4v[4];
        uint32_t lsum = 0;
#pragma unroll
        for (int j = 0; j < 4; ++j) { c4v[j] = csums[tid * 4 + j]; lsum += c4v[j]; }
        part[tid] = lsum;
        __syncthreads();
        for (int off = 1; off < 256; off <<= 1) {
            uint32_t add = (tid + off < 256) ? part[tid + off] : 0u;
            __syncthreads();
            part[tid] += add;
            __syncthreads();
        }
        uint32_t A = (tid < 255) ? part[tid + 1] : 0u;
#pragma unroll
        for (int j = 3; j >= 0; --j) {
            uint32_t c = c4v[j];
            if (A < k1rem && k1rem <= A + c) { bc[5] = (uint32_t)(tid * 4 + j); bc[6] = k1rem - A; }
            A += c;
        }
        __syncthreads();
        const uint32_t chunk = bc[5];
        const uint32_t k2 = bc[6];

        const uint32_t* base = h21 + (size_t)chunk * 2048;
        uint32_t b8[8];
        lsum = 0;
#pragma unroll
        for (int j = 0; j < 8; ++j) { b8[j] = base[tid * 8 + j]; lsum += b8[j]; }
        part[tid] = lsum;
        __syncthreads();
        for (int off = 1; off < 256; off <<= 1) {
            uint32_t add = (tid + off < 256) ? part[tid + off] : 0u;
            __syncthreads();
            part[tid] += add;
            __syncthreads();
        }
        A = (tid < 255) ? part[tid + 1] : 0u;
#pragma unroll
        for (int j = 7; j >= 0; --j) {
            uint32_t c = b8[j];
            if (A < k2 && k2 <= A + c) {
                uint32_t u = (prefix1 << 21) | (chunk * 2048u + (uint32_t)(tid * 8 + j));
                bc[3] = u;
                bc[4] = __float_as_uint(neg_loss_precise(unxform(u), -1.0f));
            }
            A += c;
        }
        __syncthreads();
    }
    const uint32_t ukth = bc[3];
    const float thr = __uint_as_float(bc[4]);

    // ---- P6: final output ----
    {
        float4* o4 = (float4*)out;
        int i2 = bid * 256 + tid;
        for (; i2 + 3 * S < n4; i2 += 4 * S) {
            float4 xa = x4[i2], xb = x4[i2 + S], xc = x4[i2 + 2 * S], xd = x4[i2 + 3 * S];
            uint32_t ca = cmap[i2], cb = cmap[i2 + S], cc = cmap[i2 + 2 * S], cd = cmap[i2 + 3 * S];
            o4[i2]         = fin_quadc(xa, ca, ukth, thr);
            o4[i2 + S]     = fin_quadc(xb, cb, ukth, thr);
            o4[i2 + 2 * S] = fin_quadc(xc, cc, ukth, thr);
            o4[i2 + 3 * S] = fin_quadc(xd, cd, ukth, thr);
        }
        for (; i2 < n4; i2 += S) {
            float4 xa = x4[i2];
            uint32_t ca = cmap[i2];
            o4[i2] = fin_quadc(xa, ca, ukth, thr);
        }
        if (bid == 0) {
            for (int j = (n4 << 2) + tid; j < n; j += 256) {
                out[j] = fin1t(x[j], t[j], ukth, thr);
            }
        }
    }
}

// =====================================================================
// Legacy R8 chain (fallback if cooperative launch is unavailable)
// =====================================================================
__global__ __launch_bounds__(256) void k1_hist(
        const float* __restrict__ x, const float* __restrict__ t,
        uint32_t* __restrict__ hrep, uint32_t* __restrict__ cand1,
        uint32_t* __restrict__ wvcnt, uint8_t* __restrict__ cmap,
        int n, int segw) {
    __shared__ uint32_t lh[2 * 2049];
    for (int j = threadIdx.x; j < 2 * 2049; j += 256) lh[j] = 0;
    __syncthreads();
    uint32_t* my = &lh[(threadIdx.x & 1) * 2049];

    const float4* x4 = (const float4*)x;
    const float4* t4 = (const float4*)t;
    const int n4 = n >> 2;
    const int S = gridDim.x * 256;
    const int lane = threadIdx.x & 63;
    const int wid  = threadIdx.x >> 6;
    uint32_t* wseg = cand1 + (size_t)(blockIdx.x * 4 + wid) * (size_t)segw;
    uint32_t wcur = 0;

    int M4 = 0;
    {
        long rem = (long)n4 - 1 - (long)(blockIdx.x * 256 + 255);
        if (rem >= 0) {
            long T = rem / S;
            if (T >= 3) M4 = (int)((T - 3) / 4 + 1);
        }
    }
    int i = blockIdx.x * 256 + threadIdx.x;

    for (int b = 0; b < M4; ++b, i += 4 * S) {
        float4 xa = x4[i], xb = x4[i + S], xc = x4[i + 2 * S], xd = x4[i + 3 * S];
        float4 ta = t4[i], tb = t4[i + S], tc = t4[i + 2 * S], td = t4[i + 3 * S];
        uint32_t u0, u1, u2, u3, u4_, u5, u6, u7, u8, u9, uA, uB, uC, uD, uE, uF;
        uint32_t ca = quad_u_cls(my, xa, ta, u0, u1, u2, u3);
        uint32_t cb = quad_u_cls(my, xb, tb, u4_, u5, u6, u7);
        uint32_t cc = quad_u_cls(my, xc, tc, u8, u9, uA, uB);
        uint32_t cd = quad_u_cls(my, xd, td, uC, uD, uE, uF);
        cmap[i]         = (uint8_t)ca;
        cmap[i + S]     = (uint8_t)cb;
        cmap[i + 2 * S] = (uint8_t)cc;
        cmap[i + 3 * S] = (uint8_t)cd;
        uint32_t m = (u0 != 0) + (u1 != 0) + (u2 != 0) + (u3 != 0)
                   + (u4_ != 0) + (u5 != 0) + (u6 != 0) + (u7 != 0)
                   + (u8 != 0) + (u9 != 0) + (uA != 0) + (uB != 0)
                   + (uC != 0) + (uD != 0) + (uE != 0) + (uF != 0);
        uint32_t excl, tot;
        wscan(m, lane, excl, tot);
        uint32_t p = wcur + excl;
        if (u0)  wseg[p++] = u0;
        if (u1)  wseg[p++] = u1;
        if (u2)  wseg[p++] = u2;
        if (u3)  wseg[p++] = u3;
        if (u4_) wseg[p++] = u4_;
        if (u5)  wseg[p++] = u5;
        if (u6)  wseg[p++] = u6;
        if (u7)  wseg[p++] = u7;
        if (u8)  wseg[p++] = u8;
        if (u9)  wseg[p++] = u9;
        if (uA)  wseg[p++] = uA;
        if (uB)  wseg[p++] = uB;
        if (uC)  wseg[p++] = uC;
        if (uD)  wseg[p++] = uD;
        if (uE)  wseg[p++] = uE;
        if (uF)  wseg[p++] = uF;
        wcur += tot;
    }

    for (; __any(i < n4); i += S) {
        const bool act = i < n4;
        float4 xa = act ? x4[i] : make_float4(0.f, 0.f, 0.f, 0.f);
        float4 ta = act ? t4[i] : make_float4(0.f, 0.f, 0.f, 0.f);
        uint32_t u0, u1, u2, u3;
        uint32_t ca = quad_u_cls(my, xa, ta, u0, u1, u2, u3);
        if (act) cmap[i] = (uint8_t)ca;
        uint32_t m = (u0 != 0) + (u1 != 0) + (u2 != 0) + (u3 != 0);
        uint32_t excl, tot;
        wscan(m, lane, excl, tot);
        uint32_t p = wcur + excl;
        if (u0) wseg[p++] = u0;
        if (u1) wseg[p++] = u1;
        if (u2) wseg[p++] = u2;
        if (u3) wseg[p++] = u3;
        wcur += tot;
    }

    if (blockIdx.x == 0) {
        int j = (n4 << 2) + threadIdx.x;
        const bool act = j < n;
        float xx = act ? x[j] : 0.0f;
        float tt = act ? t[j] : 0.0f;
        uint32_t u0 = (tt < 0.0f) ? xform(__float_as_uint(xx)) : 0u;
        if (u0) atomicAdd(&my[u0 >> 21], 1u);
        uint32_t excl, tot;
        wscan(u0 != 0 ? 1u : 0u, lane, excl, tot);
        if (u0) wseg[wcur + excl] = u0;
        wcur += tot;
    }

    if (lane == 0) wvcnt[blockIdx.x * 4 + wid] = wcur;

    __syncthreads();
    uint32_t* hmine = hrep + (size_t)(blockIdx.x & (HREP - 1)) * 2048;
    for (int b2 = threadIdx.x; b2 < 2048; b2 += 256) {
        uint32_t c = lh[b2] + lh[2049 + b2];
        if (c) atomicAdd(&hmine[b2], c);
    }
}

__global__ __launch_bounds__(256) void s1_scan(
        const uint32_t* __restrict__ hrep, SelState* __restrict__ st,
        const int* __restrict__ kptr) {
    __shared__ uint32_t part[256];
    const int tid = threadIdx.x;
    uint32_t cnt[8];
    uint32_t lsum = 0;
#pragma unroll
    for (int j = 0; j < 8; ++j) {
        uint32_t c = 0;
#pragma unroll
        for (int r = 0; r < HREP; ++r) c += hrep[r * 2048 + tid * 8 + j];
        cnt[j] = c;
        lsum += c;
    }
    part[tid] = lsum;
    __syncthreads();
    for (int off = 1; off < 256; off <<= 1) {
        uint32_t add = (tid + off < 256) ? part[tid + off] : 0u;
        __syncthreads();
        part[tid] += add;
        __syncthreads();
    }
    const uint32_t total = part[0];
    int kk = *kptr;
    uint32_t k = (kk > 0) ? (uint32_t)kk : 0u;
    if (k == 0u) {
        if (tid == 0) { st->u_kth = 0xFFFFFFFFu; st->thr_nl = __int_as_float(0x7F800000); st->done = 1u; }
        return;
    }
    if (k > total) {
        if (tid == 0) { st->u_kth = 0u; st->thr_nl = 0.0f; st->done = 1u; }
        return;
    }
    uint32_t A = (tid < 255) ? part[tid + 1] : 0u;
#pragma unroll
    for (int j = 7; j >= 0; --j) {
        uint32_t c = cnt[j];
        if (A < k && k <= A + c) {
            st->prefix1 = (uint32_t)(tid * 8 + j);
            st->k1rem = k - A;
        }
        A += c;
    }
}

__global__ __launch_bounds__(256) void k2_sel21(
        const uint32_t* __restrict__ cand1, const uint32_t* __restrict__ wvcnt,
        uint32_t* __restrict__ h21, const SelState* __restrict__ st, int segw) {
    __shared__ uint32_t s_pref, s_done;
    if (threadIdx.x == 0) { s_pref = st->prefix1; s_done = st->done; }
    __syncthreads();
    if (s_done) return;
    const uint32_t pref = s_pref;
    const int lane = threadIdx.x & 63;
    const int wid  = threadIdx.x >> 6;
    const int sidx = blockIdx.x * 4 + wid;
    const uint32_t cnt = wvcnt[sidx];
    const uint4* b4 = (const uint4*)(cand1 + (size_t)sidx * (size_t)segw);
    const uint32_t iters = (cnt + 255u) >> 8;
    for (uint32_t it = 0; it < iters; ++it) {
        const uint32_t e0 = it * 256u + (uint32_t)lane * 4u;
        uint4 v = b4[it * 64u + (uint32_t)lane];
        if (e0 + 0u < cnt && (v.x >> 21) == pref) atomicAdd(&h21[v.x & 0x1FFFFFu], 1u);
        if (e0 + 1u < cnt && (v.y >> 21) == pref) atomicAdd(&h21[v.y & 0x1FFFFFu], 1u);
        if (e0 + 2u < cnt && (v.z >> 21) == pref) atomicAdd(&h21[v.z & 0x1FFFFFu], 1u);
        if (e0 + 3u < cnt && (v.w >> 21) == pref) atomicAdd(&h21[v.w & 0x1FFFFFu], 1u);
    }
}

__global__ __launch_bounds__(256) void scan2a(
        const uint32_t* __restrict__ h21, uint32_t* __restrict__ csums,
        const SelState* __restrict__ st) {
    __shared__ uint32_t red[256];
    __shared__ uint32_t s_done;
    if (threadIdx.x == 0) s_done = st->done;
    __syncthreads();
    if (s_done) return;
    const uint4* b4 = (const uint4*)(h21 + (size_t)blockIdx.x * 2048);
    uint32_t s = 0;
    for (int j = threadIdx.x; j < 512; j += 256) {
        uint4 v = b4[j];
        s += v.x + v.y + v.z + v.w;
    }
    red[threadIdx.x] = s;
    __syncthreads();
    for (int off = 128; off > 0; off >>= 1) {
        if (threadIdx.x < off) red[threadIdx.x] += red[threadIdx.x + off];
        __syncthreads();
    }
    if (threadIdx.x == 0) csums[blockIdx.x] = red[0];
}

__global__ __launch_bounds__(256) void scan2b(
        const uint32_t* __restrict__ h21, const uint32_t* __restrict__ csums,
        SelState* __restrict__ st) {
    __shared__ uint32_t part[256];
    __shared__ uint32_t sel[2];
    __shared__ SelState sst;
    const int tid = threadIdx.x;
    if (tid == 0) sst = *st;
    __syncthreads();
    if (sst.done) return;
    const uint32_t k = sst.k1rem;

    uint32_t c4[4];
    uint32_t lsum = 0;
#pragma unroll
    for (int j = 0; j < 4; ++j) { c4[j] = csums[tid * 4 + j]; lsum += c4[j]; }
    part[tid] = lsum;
    __syncthreads();
    for (int off = 1; off < 256; off <<= 1) {
        uint32_t add = (tid + off < 256) ? part[tid + off] : 0u;
        __syncthreads();
        part[tid] += add;
        __syncthreads();
    }
    uint32_t A = (tid < 255) ? part[tid + 1] : 0u;
#pragma unroll
    for (int j = 3; j >= 0; --j) {
        uint32_t c = c4[j];
        if (A < k && k <= A + c) { sel[0] = (uint32_t)(tid * 4 + j); sel[1] = k - A; }
        A += c;
    }
    __syncthreads();
    const uint32_t chunk = sel[0];
    const uint32_t k2 = sel[1];
    __syncthreads();

    const uint32_t* base = h21 + (size_t)chunk * 2048;
    uint32_t b8[8];
    lsum = 0;
#pragma unroll
    for (int j = 0; j < 8; ++j) { b8[j] = base[tid * 8 + j]; lsum += b8[j]; }
    part[tid] = lsum;
    __syncthreads();
    for (int off = 1; off < 256; off <<= 1) {
        uint32_t add = (tid + off < 256) ? part[tid + off] : 0u;
        __syncthreads();
        part[tid] += add;
        __syncthreads();
    }
    A = (tid < 255) ? part[tid + 1] : 0u;
#pragma unroll
    for (int j = 7; j >= 0; --j) {
        uint32_t c = b8[j];
        if (A < k2 && k2 <= A + c) {
            uint32_t u = (sst.prefix1 << 21) | (chunk * 2048u + (uint32_t)(tid * 8 + j));
            st->u_kth = u;
            st->thr_nl = neg_loss_precise(unxform(u), -1.0f);
            st->done = 1u;
        }
        A += c;
    }
}

__global__ __launch_bounds__(256) void k_final(
        const float* __restrict__ x, const float* __restrict__ t,
        const uint8_t* __restrict__ cmap, const SelState* __restrict__ st,
        float* __restrict__ out, int n) {
    const uint32_t ukth = st->u_kth;
    const float thr = st->thr_nl;
    const float4* x4 = (const float4*)x;
    float4* o4 = (float4*)out;
    const int n4 = n >> 2;
    const int S = gridDim.x * 256;
    int i = blockIdx.x * 256 + threadIdx.x;
    for (; i + 3 * S < n4; i += 4 * S) {
        float4 xa = x4[i], xb = x4[i + S], xc = x4[i + 2 * S], xd = x4[i + 3 * S];
        uint32_t ca = cmap[i], cb = cmap[i + S], cc = cmap[i + 2 * S], cd = cmap[i + 3 * S];
        o4[i]         = fin_quadc(xa, ca, ukth, thr);
        o4[i + S]     = fin_quadc(xb, cb, ukth, thr);
        o4[i + 2 * S] = fin_quadc(xc, cc, ukth, thr);
        o4[i + 3 * S] = fin_quadc(xd, cd, ukth, thr);
    }
    for (; i < n4; i += S) {
        float4 xa = x4[i];
        uint32_t ca = cmap[i];
        o4[i] = fin_quadc(xa, ca, ukth, thr);
    }
    if (blockIdx.x == 0) {
        for (int j = (n4 << 2) + threadIdx.x; j < n; j += 256) {
            out[j] = fin1t(x[j], t[j], ukth, thr);
        }
    }
}

// =====================================================================
extern "C" void kernel_launch(void* const* d_in, const int* in_sizes, int n_in,
                              void* d_out, int out_size, void* d_ws, size_t ws_size,
                              hipStream_t stream) {
    const float* x = (const float*)d_in[0];
    const float* t = (const float*)d_in[1];
    const int* kptr = (const int*)d_in[2];
    float* out = (float*)d_out;
    const int n = in_sizes[0];
    if (n <= 0) return;

    // one-time occupancy probe for the cooperative grid limit
    static int g_maxblk = 0;
    static int g_coop = -1;   // -1 unknown, 1 works, 0 fall back to chain
    if (g_maxblk == 0) {
        int perCU = 0;
        if (hipOccupancyMaxActiveBlocksPerMultiprocessor(&perCU, fused, 256, 0) != hipSuccess || perCU < 1)
            perCU = 0;
        int ncu = 0;
        int dev = 0;
        hipGetDevice(&dev);
        if (hipDeviceGetAttribute(&ncu, hipDeviceAttributeMultiprocessorCount, dev) != hipSuccess || ncu < 1)
            ncu = 0;
        long mb = (long)perCU * (long)ncu;
        if (mb <= 0) mb = 512;                 // conservative fallback
        g_maxblk = (int)(mb > 1024 ? 1024 : mb);
    }

    const int n4 = n >> 2;
    int work = (n4 + 255) / 256;
    if (work < 1) work = 1;
    int grid = work < g_maxblk ? work : g_maxblk;
    if (grid > 1024) grid = 1024;
    const int S = grid * 256;
    const int Q = (n4 + S - 1) / S;
    const int segw = 256 * Q + 4;
    const int nseg = grid * 4;

    char* ws = (char*)d_ws;
    uint32_t* hrep  = (uint32_t*)(ws + 0);          // 8 x 2048 u32 (64 KB)
    SelState* st    = (SelState*)(ws + 65536);      // legacy path only
    uint32_t* h21   = (uint32_t*)(ws + 65792);      // 2^21 u32 (8 MB)
    size_t csoff = 65792 + ((size_t)1u << 21) * 4u; // 8454400
    uint32_t* csums = (uint32_t*)(ws + csoff);      // 1024 u32
    uint32_t* wvcnt = (uint32_t*)(ws + csoff + 4096);  // legacy path only
    size_t cmoff = csoff + 4096 + 16384;
    uint8_t*  cmap  = (uint8_t*)(ws + cmoff);       // n4 bytes
    size_t c1off = (cmoff + (size_t)n4 + 255) & ~(size_t)255;
    uint32_t* cand1 = (uint32_t*)(ws + c1off);      // nseg*segw u32

    if (g_coop != 0) {
        int n_arg = n, segw_arg = segw;
        void* args[] = { (void*)&x, (void*)&t, (void*)&kptr,
                         (void*)&hrep, (void*)&h21, (void*)&csums,
                         (void*)&cand1, (void*)&cmap, (void*)&out,
                         (void*)&n_arg, (void*)&segw_arg };
        hipError_t err = hipLaunchCooperativeKernel((const void*)fused,
                                                    dim3(grid), dim3(256),
                                                    args, 0, stream);
        if (err == hipSuccess) { g_coop = 1; return; }
        g_coop = 0;   // capture-time rejection -> legacy chain from now on
    }

    // ---- legacy R8 chain ----
    hipMemsetAsync(d_ws, 0, csoff, stream);
    k1_hist <<<grid, 256, 0, stream>>>(x, t, hrep, cand1, wvcnt, cmap, n, segw);
    s1_scan <<<1, 256, 0, stream>>>(hrep, st, kptr);
    k2_sel21<<<grid, 256, 0, stream>>>(cand1, wvcnt, h21, st, segw);
    scan2a  <<<1024, 256, 0, stream>>>(h21, csums, st);
    scan2b  <<<1, 256, 0, stream>>>(h21, csums, st);
    k_final <<<grid, 256, 0, stream>>>(x, t, cmap, st, out, n);
    (void)nseg;
}

// Round 6
// 164.367 us; speedup vs baseline: 2.9565x; 2.9565x over previous
//
#include <hip/hip_runtime.h>
#include <cstdint>
#include <cstddef>

// Exact radix select on order-transformed x bits among t<0 entries
// (t = -1 exactly => negative_loss = softplus(x), strictly increasing in x).
//
// R10: R8's validated dataflow in 5 dispatches (was 7).
//   fill(64KB):zero hrep only (h21 zeroing moved into k1).
//   k1:        zero h21 (grid-stride, consumed next dispatch = race-free);
//              stream x,t (82 MB): 2048-bin LDS hist (bits31:21) -> 8-way
//              replicated global hist (atomic merge; replicas kill the
//              R5-style line ping-pong); compact negatives' u into per-wave
//              cand1 segments (no atomics); 2-bit class map.
//   k2s:       every block REDUNDANTLY rank-selects prefix1 from hrep
//              (64 KB L3-hot broadcast; replaces the s1 dispatch); block 0
//              writes SelState; then each wave filters its own cand1 segment
//              and scatter-atomics into 2^21-bin h21 (scattered lines ->
//              no ping-pong; proven R0/R8).
//   scan2a:    1024 blocks — per-chunk sums of h21 (stateless; in done-mode
//              h21 is all zeros and csums are harmlessly zero).
//   kf:        every block REDUNDANTLY picks chunk+bin from csums/h21
//              (12 KB L3-hot; replaces the scan2b dispatch) -> u_kth + thr;
//              then final pass: x + cmap, fast __expf/__logf values,
//              bit-exact mask, precise re-check in 256-ulp guard band.
//
// Ledger (measured):
//   R5:  140k device atomics on 4 KB hist -> line ping-pong, 47 us. BAD.
//   R6:  single block over scattered segs -> latency chain, 76 us. BAD.
//   R7:  single block streaming ~1 MB x2  -> single-CU BW bound. MEH.
//   R8:  scattered 2^21 scatter + replicated hist merge, 7 dispatches: 167 us.
//   R9:  cg::grid.sync costs ~100 us/barrier at 1024 blocks (486 us). BAD.
//   R10: dispatch-count cut via redundant block-local selects.

struct SelState {
    uint32_t done;
    uint32_t prefix1;  // 11-bit level-1 prefix (bits 31:21)
    uint32_t k1rem;    // remaining rank within level-1 bin (1-based)
    uint32_t u_kth;    // done-mode: final transformed bits
    float    thr_nl;   // done-mode: loss-space threshold
};

#define GUARD 256u
#define HREP 8

__device__ __forceinline__ uint32_t xform(uint32_t b) {
    return ((int32_t)b < 0) ? ~b : (b | 0x80000000u);
}
__device__ __forceinline__ float unxform(uint32_t u) {
    uint32_t b = (u & 0x80000000u) ? (u ^ 0x80000000u) : ~u;
    return __uint_as_float(b);
}
// precise chain — matches reference fp32 semantics; used only for the
// threshold value and the rare guard-band compare.
__device__ __forceinline__ float neg_loss_precise(float x, float t) {
#pragma clang fp contract(off)
    return (fmaxf(-x, 0.0f) - x * t) + log1pf(expf(-fabsf(x)));
}

// wave-wide inclusive scan -> exclusive offset + total (64 lanes)
__device__ __forceinline__ void wscan(uint32_t m, int lane, uint32_t& excl, uint32_t& tot) {
    uint32_t inc = m;
#pragma unroll
    for (int d = 1; d < 64; d <<= 1) {
        uint32_t v = __shfl_up(inc, (unsigned)d, 64);
        if (lane >= d) inc += v;
    }
    excl = inc - m;
    tot = __shfl(inc, 63, 64);
}

// per-quad: u values (0 if not negative), class byte, LDS histogram
__device__ __forceinline__ uint32_t quad_u_cls(uint32_t* my, float4 xv, float4 tv,
        uint32_t& u0, uint32_t& u1, uint32_t& u2, uint32_t& u3) {
    u0 = (tv.x < 0.0f) ? xform(__float_as_uint(xv.x)) : 0u;
    u1 = (tv.y < 0.0f) ? xform(__float_as_uint(xv.y)) : 0u;
    u2 = (tv.z < 0.0f) ? xform(__float_as_uint(xv.z)) : 0u;
    u3 = (tv.w < 0.0f) ? xform(__float_as_uint(xv.w)) : 0u;
    uint32_t cls = ((tv.x > 0.0f) ? 1u : ((tv.x < 0.0f) ? 2u : 0u))
                 | (((tv.y > 0.0f) ? 1u : ((tv.y < 0.0f) ? 2u : 0u)) << 2)
                 | (((tv.z > 0.0f) ? 1u : ((tv.z < 0.0f) ? 2u : 0u)) << 4)
                 | (((tv.w > 0.0f) ? 1u : ((tv.w < 0.0f) ? 2u : 0u)) << 6);
    if (u0) atomicAdd(&my[u0 >> 21], 1u);
    if (u1) atomicAdd(&my[u1 >> 21], 1u);
    if (u2) atomicAdd(&my[u2 >> 21], 1u);
    if (u3) atomicAdd(&my[u3 >> 21], 1u);
    return cls;
}

// ---------- k1: zero h21 + 11-bit LDS hist + compaction + class map ----------
__global__ __launch_bounds__(256) void k1_hist(
        const float* __restrict__ x, const float* __restrict__ t,
        uint32_t* __restrict__ hrep, uint32_t* __restrict__ h21,
        uint32_t* __restrict__ cand1, uint32_t* __restrict__ wvcnt,
        uint8_t* __restrict__ cmap, int n, int segw) {
    const int S = gridDim.x * 256;
    const int gtid = blockIdx.x * 256 + threadIdx.x;

    // zero h21 for this iteration (consumed only in the NEXT dispatch)
    {
        uint4* h4 = (uint4*)h21;
        uint4 z; z.x = 0u; z.y = 0u; z.z = 0u; z.w = 0u;
        for (int j = gtid; j < (1 << 19); j += S) h4[j] = z;
    }

    __shared__ uint32_t lh[2 * 2049];   // 2-way replicated (+1 pad)
    for (int j = threadIdx.x; j < 2 * 2049; j += 256) lh[j] = 0;
    __syncthreads();
    uint32_t* my = &lh[(threadIdx.x & 1) * 2049];

    const float4* x4 = (const float4*)x;
    const float4* t4 = (const float4*)t;
    const int n4 = n >> 2;
    const int lane = threadIdx.x & 63;
    const int wid  = threadIdx.x >> 6;
    uint32_t* wseg = cand1 + (size_t)(blockIdx.x * 4 + wid) * (size_t)segw;
    uint32_t wcur = 0;   // wave-uniform segment cursor (no atomics)

    // block-uniform count of full 4x-unrolled batches (appends use wave-wide
    // shfl scans, so the unrolled loop must be wave-uniform)
    int M4 = 0;
    {
        long rem = (long)n4 - 1 - (long)(blockIdx.x * 256 + 255);
        if (rem >= 0) {
            long T = rem / S;
            if (T >= 3) M4 = (int)((T - 3) / 4 + 1);
        }
    }
    int i = blockIdx.x * 256 + threadIdx.x;

    for (int b = 0; b < M4; ++b, i += 4 * S) {   // 8 independent 16B loads in flight
        float4 xa = x4[i], xb = x4[i + S], xc = x4[i + 2 * S], xd = x4[i + 3 * S];
        float4 ta = t4[i], tb = t4[i + S], tc = t4[i + 2 * S], td = t4[i + 3 * S];
        uint32_t u0, u1, u2, u3, u4_, u5, u6, u7, u8, u9, uA, uB, uC, uD, uE, uF;
        uint32_t ca = quad_u_cls(my, xa, ta, u0, u1, u2, u3);
        uint32_t cb = quad_u_cls(my, xb, tb, u4_, u5, u6, u7);
        uint32_t cc = quad_u_cls(my, xc, tc, u8, u9, uA, uB);
        uint32_t cd = quad_u_cls(my, xd, td, uC, uD, uE, uF);
        cmap[i]         = (uint8_t)ca;
        cmap[i + S]     = (uint8_t)cb;
        cmap[i + 2 * S] = (uint8_t)cc;
        cmap[i + 3 * S] = (uint8_t)cd;
        uint32_t m = (u0 != 0) + (u1 != 0) + (u2 != 0) + (u3 != 0)
                   + (u4_ != 0) + (u5 != 0) + (u6 != 0) + (u7 != 0)
                   + (u8 != 0) + (u9 != 0) + (uA != 0) + (uB != 0)
                   + (uC != 0) + (uD != 0) + (uE != 0) + (uF != 0);
        uint32_t excl, tot;
        wscan(m, lane, excl, tot);
        uint32_t p = wcur + excl;
        if (u0)  wseg[p++] = u0;
        if (u1)  wseg[p++] = u1;
        if (u2)  wseg[p++] = u2;
        if (u3)  wseg[p++] = u3;
        if (u4_) wseg[p++] = u4_;
        if (u5)  wseg[p++] = u5;
        if (u6)  wseg[p++] = u6;
        if (u7)  wseg[p++] = u7;
        if (u8)  wseg[p++] = u8;
        if (u9)  wseg[p++] = u9;
        if (uA)  wseg[p++] = uA;
        if (uB)  wseg[p++] = uB;
        if (uC)  wseg[p++] = uC;
        if (uD)  wseg[p++] = uD;
        if (uE)  wseg[p++] = uE;
        if (uF)  wseg[p++] = uF;
        wcur += tot;
    }

    // masked single-quad remainder (wave-uniform loop via __any)
    for (; __any(i < n4); i += S) {
        const bool act = i < n4;
        float4 xa = act ? x4[i] : make_float4(0.f, 0.f, 0.f, 0.f);
        float4 ta = act ? t4[i] : make_float4(0.f, 0.f, 0.f, 0.f);
        uint32_t u0, u1, u2, u3;
        uint32_t ca = quad_u_cls(my, xa, ta, u0, u1, u2, u3);
        if (act) cmap[i] = (uint8_t)ca;
        uint32_t m = (u0 != 0) + (u1 != 0) + (u2 != 0) + (u3 != 0);
        uint32_t excl, tot;
        wscan(m, lane, excl, tot);
        uint32_t p = wcur + excl;
        if (u0) wseg[p++] = u0;
        if (u1) wseg[p++] = u1;
        if (u2) wseg[p++] = u2;
        if (u3) wseg[p++] = u3;
        wcur += tot;
    }

    // n % 4 tail (block 0 only; <4 elems; no cmap — kf reads t for tail)
    if (blockIdx.x == 0) {
        int j = (n4 << 2) + threadIdx.x;
        const bool act = j < n;
        float xx = act ? x[j] : 0.0f;
        float tt = act ? t[j] : 0.0f;
        uint32_t u0 = (tt < 0.0f) ? xform(__float_as_uint(xx)) : 0u;
        if (u0) atomicAdd(&my[u0 >> 21], 1u);
        uint32_t excl, tot;
        wscan(u0 != 0 ? 1u : 0u, lane, excl, tot);
        if (u0) wseg[wcur + excl] = u0;
        wcur += tot;
    }

    if (lane == 0) wvcnt[blockIdx.x * 4 + wid] = wcur;

    __syncthreads();
    // 8-way replicated global hist merge (spreads RMWs across 8x lines)
    uint32_t* hmine = hrep + (size_t)(blockIdx.x & (HREP - 1)) * 2048;
    for (int b2 = threadIdx.x; b2 < 2048; b2 += 256) {
        uint32_t c = lh[b2] + lh[2049 + b2];
        if (c) atomicAdd(&hmine[b2], c);
    }
}

// ---------- k2s: redundant prefix1-select (replaces s1) + scatter ----------
__global__ __launch_bounds__(256) void k2s(
        const uint32_t* __restrict__ hrep, const int* __restrict__ kptr,
        const uint32_t* __restrict__ cand1, const uint32_t* __restrict__ wvcnt,
        uint32_t* __restrict__ h21, SelState* __restrict__ st, int segw) {
    __shared__ uint32_t part[256];
    __shared__ uint32_t bc[2];
    const int tid = threadIdx.x;

    // redundant s1: every block reads the 64 KB hrep (L2/L3-hot broadcast)
    uint32_t cnt8[8];
    uint32_t lsum = 0;
#pragma unroll
    for (int j = 0; j < 8; ++j) {
        uint32_t c = 0;
#pragma unroll
        for (int r = 0; r < HREP; ++r) c += hrep[r * 2048 + tid * 8 + j];
        cnt8[j] = c;
        lsum += c;
    }
    part[tid] = lsum;
    __syncthreads();
    for (int off = 1; off < 256; off <<= 1) {   // inclusive suffix sum
        uint32_t add = (tid + off < 256) ? part[tid + off] : 0u;
        __syncthreads();
        part[tid] += add;
        __syncthreads();
    }
    const uint32_t total = part[0];
    int kk = *kptr;
    uint32_t k = (kk > 0) ? (uint32_t)kk : 0u;
    if (k == 0u) {          // keep all negatives
        if (blockIdx.x == 0 && tid == 0) {
            st->done = 1u; st->u_kth = 0xFFFFFFFFu; st->thr_nl = __int_as_float(0x7F800000);
        }
        return;             // h21 stays zeroed -> csums zero -> kf uses done path
    }
    if (k > total) {        // drop all negatives
        if (blockIdx.x == 0 && tid == 0) {
            st->done = 1u; st->u_kth = 0u; st->thr_nl = 0.0f;
        }
        return;
    }
    {
        uint32_t A = (tid < 255) ? part[tid + 1] : 0u;  // strictly-above count
#pragma unroll
        for (int j = 7; j >= 0; --j) {
            uint32_t c = cnt8[j];
            if (A < k && k <= A + c) {   // exactly one (thread,bin) per block
                bc[0] = (uint32_t)(tid * 8 + j);
                bc[1] = k - A;
                if (blockIdx.x == 0) {
                    st->done = 0u;
                    st->prefix1 = (uint32_t)(tid * 8 + j);
                    st->k1rem = k - A;
                }
            }
            A += c;
        }
    }
    __syncthreads();
    const uint32_t prefix1 = bc[0];

    // scatter own cand1 segment into the 2^21-bin histogram
    const int lane = tid & 63;
    const int wid  = tid >> 6;
    const int sidx = blockIdx.x * 4 + wid;   // same index k1 wrote: L2-local
    const uint32_t cnt = wvcnt[sidx];
    const uint4* b4 = (const uint4*)(cand1 + (size_t)sidx * (size_t)segw);
    const uint32_t iters = (cnt + 255u) >> 8;
    for (uint32_t it = 0; it < iters; ++it) {
        const uint32_t e0 = it * 256u + (uint32_t)lane * 4u;
        uint4 v = b4[it * 64u + (uint32_t)lane];   // in-bounds: cnt<=256*Q<=segw-4
        if (e0 + 0u < cnt && (v.x >> 21) == prefix1) atomicAdd(&h21[v.x & 0x1FFFFFu], 1u);
        if (e0 + 1u < cnt && (v.y >> 21) == prefix1) atomicAdd(&h21[v.y & 0x1FFFFFu], 1u);
        if (e0 + 2u < cnt && (v.z >> 21) == prefix1) atomicAdd(&h21[v.z & 0x1FFFFFu], 1u);
        if (e0 + 3u < cnt && (v.w >> 21) == prefix1) atomicAdd(&h21[v.w & 0x1FFFFFu], 1u);
    }
}

// ---------------- scan2a: per-chunk sums of h21 (stateless) ----------------
__global__ __launch_bounds__(256) void scan2a(
        const uint32_t* __restrict__ h21, uint32_t* __restrict__ csums) {
    __shared__ uint32_t red[256];
    const uint4* b4 = (const uint4*)(h21 + (size_t)blockIdx.x * 2048);
    uint32_t s = 0;
    for (int j = threadIdx.x; j < 512; j += 256) {
        uint4 v = b4[j];
        s += v.x + v.y + v.z + v.w;
    }
    red[threadIdx.x] = s;
    __syncthreads();
    for (int off = 128; off > 0; off >>= 1) {
        if (threadIdx.x < off) red[threadIdx.x] += red[threadIdx.x + off];
        __syncthreads();
    }
    if (threadIdx.x == 0) csums[blockIdx.x] = red[0];
}

// ---------------- final-pass value helpers ----------------
__device__ __forceinline__ float fin1c(float xx, uint32_t cls, uint32_t ukth, float thr) {
    float lp = __logf(1.0f + __expf(-fabsf(xx)));   // HW exp/log
    float v = 0.0f;
    if (cls == 1u) {                    // t = +1
        v = (fmaxf(xx, 0.0f) - xx) + lp;
    } else if (cls == 2u) {             // t = -1
        uint32_t u = xform(__float_as_uint(xx));
        bool keep = u < ukth;
        if (keep && (ukth - u) < GUARD)             // ~0 lanes hit this
            keep = neg_loss_precise(xx, -1.0f) < thr;
        if (keep) v = (fmaxf(-xx, 0.0f) + xx) + lp;
    }
    return v;
}
__device__ __forceinline__ float4 fin_quadc(float4 xv, uint32_t cb, uint32_t ukth, float thr) {
    float4 r;
    r.x = fin1c(xv.x, cb & 3u, ukth, thr);
    r.y = fin1c(xv.y, (cb >> 2) & 3u, ukth, thr);
    r.z = fin1c(xv.z, (cb >> 4) & 3u, ukth, thr);
    r.w = fin1c(xv.w, (cb >> 6) & 3u, ukth, thr);
    return r;
}
__device__ __forceinline__ float fin1t(float xx, float tt, uint32_t ukth, float thr) {
    float lp = __logf(1.0f + __expf(-fabsf(xx)));
    float v = 0.0f;
    if (tt > 0.0f) {
        v = fmaxf(xx, 0.0f) - xx * tt + lp;
    } else if (tt < 0.0f) {
        uint32_t u = xform(__float_as_uint(xx));
        bool keep = u < ukth;
        if (keep && (ukth - u) < GUARD)
            keep = neg_loss_precise(xx, tt) < thr;
        if (keep) v = fmaxf(-xx, 0.0f) - xx * tt + lp;
    }
    return v;
}

// ---------- kf: redundant chunk+bin select (replaces scan2b) + final ----------
__global__ __launch_bounds__(256) void kf(
        const float* __restrict__ x, const float* __restrict__ t,
        const uint8_t* __restrict__ cmap, const uint32_t* __restrict__ h21,
        const uint32_t* __restrict__ csums, const SelState* __restrict__ st,
        float* __restrict__ out, int n) {
    __shared__ uint32_t part[256];
    __shared__ uint32_t bc[4];   // chunk, k2, ukth, thr-bits
    __shared__ uint32_t s_done, s_pref1, s_k1rem, s_ukth, s_thr;
    const int tid = threadIdx.x;
    if (tid == 0) {
        s_done = st->done;  s_pref1 = st->prefix1;  s_k1rem = st->k1rem;
        s_ukth = st->u_kth; s_thr = __float_as_uint(st->thr_nl);
    }
    __syncthreads();

    uint32_t ukth;
    float thr;
    if (s_done) {
        ukth = s_ukth;
        thr = __uint_as_float(s_thr);
    } else {
        // redundant scan2b: csums (4 KB) + one chunk (8 KB), L3-hot broadcast
        const uint32_t k = s_k1rem;
        uint32_t c4v[4];
        uint32_t lsum = 0;
#pragma unroll
        for (int j = 0; j < 4; ++j) { c4v[j] = csums[tid * 4 + j]; lsum += c4v[j]; }
        part[tid] = lsum;
        __syncthreads();
        for (int off = 1; off < 256; off <<= 1) {
            uint32_t add = (tid + off < 256) ? part[tid + off] : 0u;
            __syncthreads();
            part[tid] += add;
            __syncthreads();
        }
        uint32_t A = (tid < 255) ? part[tid + 1] : 0u;
#pragma unroll
        for (int j = 3; j >= 0; --j) {
            uint32_t c = c4v[j];
            if (A < k && k <= A + c) { bc[0] = (uint32_t)(tid * 4 + j); bc[1] = k - A; }
            A += c;
        }
        __syncthreads();
        const uint32_t chunk = bc[0];
        const uint32_t k2 = bc[1];
        __syncthreads();

        const uint32_t* base = h21 + (size_t)chunk * 2048;
        uint32_t b8[8];
        lsum = 0;
#pragma unroll
        for (int j = 0; j < 8; ++j) { b8[j] = base[tid * 8 + j]; lsum += b8[j]; }
        part[tid] = lsum;
        __syncthreads();
        for (int off = 1; off < 256; off <<= 1) {
            uint32_t add = (tid + off < 256) ? part[tid + off] : 0u;
            __syncthreads();
            part[tid] += add;
            __syncthreads();
        }
        A = (tid < 255) ? part[tid + 1] : 0u;
#pragma unroll
        for (int j = 7; j >= 0; --j) {
            uint32_t c = b8[j];
            if (A < k2 && k2 <= A + c) {
                uint32_t u = (s_pref1 << 21) | (chunk * 2048u + (uint32_t)(tid * 8 + j));
                bc[2] = u;
                bc[3] = __float_as_uint(neg_loss_precise(unxform(u), -1.0f));  // t = -1
            }
            A += c;
        }
        __syncthreads();
        ukth = bc[2];
        thr = __uint_as_float(bc[3]);
    }

    // final output pass
    const float4* x4 = (const float4*)x;
    float4* o4 = (float4*)out;
    const int n4 = n >> 2;
    const int S = gridDim.x * 256;
    int i = blockIdx.x * 256 + tid;
    for (; i + 3 * S < n4; i += 4 * S) {
        float4 xa = x4[i], xb = x4[i + S], xc = x4[i + 2 * S], xd = x4[i + 3 * S];
        uint32_t ca = cmap[i], cb = cmap[i + S], cc = cmap[i + 2 * S], cd = cmap[i + 3 * S];
        o4[i]         = fin_quadc(xa, ca, ukth, thr);
        o4[i + S]     = fin_quadc(xb, cb, ukth, thr);
        o4[i + 2 * S] = fin_quadc(xc, cc, ukth, thr);
        o4[i + 3 * S] = fin_quadc(xd, cd, ukth, thr);
    }
    for (; i < n4; i += S) {
        float4 xa = x4[i];
        uint32_t ca = cmap[i];
        o4[i] = fin_quadc(xa, ca, ukth, thr);
    }
    if (blockIdx.x == 0) {  // n % 4 tail: no cmap — use t directly
        for (int j = (n4 << 2) + tid; j < n; j += 256) {
            out[j] = fin1t(x[j], t[j], ukth, thr);
        }
    }
}

// =====================================================================
extern "C" void kernel_launch(void* const* d_in, const int* in_sizes, int n_in,
                              void* d_out, int out_size, void* d_ws, size_t ws_size,
                              hipStream_t stream) {
    const float* x = (const float*)d_in[0];
    const float* t = (const float*)d_in[1];
    const int* kptr = (const int*)d_in[2];
    float* out = (float*)d_out;
    const int n = in_sizes[0];
    if (n <= 0) return;

    const int n4 = n >> 2;
    int work = (n4 + 255) / 256;
    if (work < 1) work = 1;
    int grid = work < 1024 ? work : 1024;   // 4 blocks/CU
    const int S = grid * 256;
    const int Q = (n4 + S - 1) / S;          // max quads per thread
    const int segw = 256 * Q + 4;            // words per wave segment (16B mult)

    char* ws = (char*)d_ws;
    uint32_t* hrep  = (uint32_t*)(ws + 0);          // 8 x 2048 u32 (64 KB)
    SelState* st    = (SelState*)(ws + 65536);      // written by k2s before kf reads
    uint32_t* h21   = (uint32_t*)(ws + 65792);      // 2^21 u32 (8 MB; zeroed by k1)
    size_t csoff = 65792 + ((size_t)1u << 21) * 4u; // 8454400
    uint32_t* csums = (uint32_t*)(ws + csoff);      // 1024 u32 (scan2a always writes)
    uint32_t* wvcnt = (uint32_t*)(ws + csoff + 4096);  // 16 KB reserved (always written)
    size_t cmoff = csoff + 4096 + 16384;
    uint8_t*  cmap  = (uint8_t*)(ws + cmoff);       // n4 bytes
    size_t c1off = (cmoff + (size_t)n4 + 255) & ~(size_t)255;
    uint32_t* cand1 = (uint32_t*)(ws + c1off);      // nseg*segw u32 (~42 MB)

    // zero ONLY hrep (64 KB) — h21 zeroing lives in k1 now
    hipMemsetAsync(d_ws, 0, 65536, stream);

    k1_hist<<<grid, 256, 0, stream>>>(x, t, hrep, h21, cand1, wvcnt, cmap, n, segw);
    k2s    <<<grid, 256, 0, stream>>>(hrep, kptr, cand1, wvcnt, h21, st, segw);
    scan2a <<<1024, 256, 0, stream>>>(h21, csums);
    kf     <<<grid, 256, 0, stream>>>(x, t, cmap, h21, csums, st, out, n);
}

// Round 7
// 162.424 us; speedup vs baseline: 2.9919x; 1.0120x over previous
//
#include <hip/hip_runtime.h>
#include <cstdint>
#include <cstddef>

// Exact radix select on order-transformed x bits among t<0 entries
// (t = -1 exactly => negative_loss = softplus(x), strictly increasing in x).
//
// R11: R10's validated dataflow in 3 BIG launches (was 4) + 96 KB memset.
//   Measured ledger: 1-block dispatches cost ~1.3 us (R10: removing two saved
//   2.7), so the ~115 us above the ~50 us traffic floor sits in the FOUR
//   full-grid launches. This round deletes one: scan2a.
//   k1:   zero h21 (consumed next dispatch = race-free); stream x,t (82 MB):
//         2048-bin LDS hist (bits31:21) -> 8-way replicated hrep merge;
//         compact negatives' u into per-wave cand1 segments (no atomics);
//         2-bit class map.
//   k2s:  every block REDUNDANTLY rank-selects prefix1 from hrep (64 KB
//         L3-hot); block 0 writes SelState; each wave filters its own cand1
//         segment, scatter-atomics into 2^21-bin h21 (scattered lines -> no
//         ping-pong) AND accumulates the survivors' chunk ids (bits[20:11])
//         in a 1024-bin LDS hist -> 8-way replicated hcoarse merge.
//         hcoarse REPLACES scan2a's csums: the chunk sums are built during
//         the scatter instead of by re-reading 8 MB in a 4th big launch.
//   kf:   every block REDUNDANTLY picks chunk (from hcoarse, 32 KB L3-hot)
//         then bin (one 8 KB chunk of h21) -> u_kth + precise thr; then the
//         final pass: x + cmap, fast __expf/__logf values, bit-exact mask,
//         precise re-check only in a 256-ulp guard band.
//
// Ledger (measured):
//   R5:  140k device atomics on 4 KB hist -> line ping-pong, 47 us. BAD.
//        (LDS-accumulate + replicated merge is the good way: k1/k2s pattern.)
//   R6:  single block over scattered segs -> latency chain, 76 us. BAD.
//   R9:  cg::grid.sync ~100 us/barrier at 1024 blocks. BAD.
//   R10: 1-block dispatch ~1.3 us; big-launch count is the remaining lever.

struct SelState {
    uint32_t done;
    uint32_t prefix1;  // 11-bit level-1 prefix (bits 31:21)
    uint32_t k1rem;    // remaining rank within level-1 bin (1-based)
    uint32_t u_kth;    // done-mode: final transformed bits
    float    thr_nl;   // done-mode: loss-space threshold
};

#define GUARD 256u
#define HREP 8

__device__ __forceinline__ uint32_t xform(uint32_t b) {
    return ((int32_t)b < 0) ? ~b : (b | 0x80000000u);
}
__device__ __forceinline__ float unxform(uint32_t u) {
    uint32_t b = (u & 0x80000000u) ? (u ^ 0x80000000u) : ~u;
    return __uint_as_float(b);
}
// precise chain — matches reference fp32 semantics; used only for the
// threshold value and the rare guard-band compare.
__device__ __forceinline__ float neg_loss_precise(float x, float t) {
#pragma clang fp contract(off)
    return (fmaxf(-x, 0.0f) - x * t) + log1pf(expf(-fabsf(x)));
}

// wave-wide inclusive scan -> exclusive offset + total (64 lanes)
__device__ __forceinline__ void wscan(uint32_t m, int lane, uint32_t& excl, uint32_t& tot) {
    uint32_t inc = m;
#pragma unroll
    for (int d = 1; d < 64; d <<= 1) {
        uint32_t v = __shfl_up(inc, (unsigned)d, 64);
        if (lane >= d) inc += v;
    }
    excl = inc - m;
    tot = __shfl(inc, 63, 64);
}

// per-quad: u values (0 if not negative), class byte, LDS histogram
__device__ __forceinline__ uint32_t quad_u_cls(uint32_t* my, float4 xv, float4 tv,
        uint32_t& u0, uint32_t& u1, uint32_t& u2, uint32_t& u3) {
    u0 = (tv.x < 0.0f) ? xform(__float_as_uint(xv.x)) : 0u;
    u1 = (tv.y < 0.0f) ? xform(__float_as_uint(xv.y)) : 0u;
    u2 = (tv.z < 0.0f) ? xform(__float_as_uint(xv.z)) : 0u;
    u3 = (tv.w < 0.0f) ? xform(__float_as_uint(xv.w)) : 0u;
    uint32_t cls = ((tv.x > 0.0f) ? 1u : ((tv.x < 0.0f) ? 2u : 0u))
                 | (((tv.y > 0.0f) ? 1u : ((tv.y < 0.0f) ? 2u : 0u)) << 2)
                 | (((tv.z > 0.0f) ? 1u : ((tv.z < 0.0f) ? 2u : 0u)) << 4)
                 | (((tv.w > 0.0f) ? 1u : ((tv.w < 0.0f) ? 2u : 0u)) << 6);
    if (u0) atomicAdd(&my[u0 >> 21], 1u);
    if (u1) atomicAdd(&my[u1 >> 21], 1u);
    if (u2) atomicAdd(&my[u2 >> 21], 1u);
    if (u3) atomicAdd(&my[u3 >> 21], 1u);
    return cls;
}

// ---------- k1: zero h21 + 11-bit LDS hist + compaction + class map ----------
__global__ __launch_bounds__(256) void k1_hist(
        const float* __restrict__ x, const float* __restrict__ t,
        uint32_t* __restrict__ hrep, uint32_t* __restrict__ h21,
        uint32_t* __restrict__ cand1, uint32_t* __restrict__ wvcnt,
        uint8_t* __restrict__ cmap, int n, int segw) {
    const int S = gridDim.x * 256;
    const int gtid = blockIdx.x * 256 + threadIdx.x;

    // zero h21 for this iteration (consumed only in the NEXT dispatch)
    {
        uint4* h4 = (uint4*)h21;
        uint4 z; z.x = 0u; z.y = 0u; z.z = 0u; z.w = 0u;
        for (int j = gtid; j < (1 << 19); j += S) h4[j] = z;
    }

    __shared__ uint32_t lh[2 * 2049];   // 2-way replicated (+1 pad)
    for (int j = threadIdx.x; j < 2 * 2049; j += 256) lh[j] = 0;
    __syncthreads();
    uint32_t* my = &lh[(threadIdx.x & 1) * 2049];

    const float4* x4 = (const float4*)x;
    const float4* t4 = (const float4*)t;
    const int n4 = n >> 2;
    const int lane = threadIdx.x & 63;
    const int wid  = threadIdx.x >> 6;
    uint32_t* wseg = cand1 + (size_t)(blockIdx.x * 4 + wid) * (size_t)segw;
    uint32_t wcur = 0;   // wave-uniform segment cursor (no atomics)

    // block-uniform count of full 4x-unrolled batches (appends use wave-wide
    // shfl scans, so the unrolled loop must be wave-uniform)
    int M4 = 0;
    {
        long rem = (long)n4 - 1 - (long)(blockIdx.x * 256 + 255);
        if (rem >= 0) {
            long T = rem / S;
            if (T >= 3) M4 = (int)((T - 3) / 4 + 1);
        }
    }
    int i = blockIdx.x * 256 + threadIdx.x;

    for (int b = 0; b < M4; ++b, i += 4 * S) {   // 8 independent 16B loads in flight
        float4 xa = x4[i], xb = x4[i + S], xc = x4[i + 2 * S], xd = x4[i + 3 * S];
        float4 ta = t4[i], tb = t4[i + S], tc = t4[i + 2 * S], td = t4[i + 3 * S];
        uint32_t u0, u1, u2, u3, u4_, u5, u6, u7, u8, u9, uA, uB, uC, uD, uE, uF;
        uint32_t ca = quad_u_cls(my, xa, ta, u0, u1, u2, u3);
        uint32_t cb = quad_u_cls(my, xb, tb, u4_, u5, u6, u7);
        uint32_t cc = quad_u_cls(my, xc, tc, u8, u9, uA, uB);
        uint32_t cd = quad_u_cls(my, xd, td, uC, uD, uE, uF);
        cmap[i]         = (uint8_t)ca;
        cmap[i + S]     = (uint8_t)cb;
        cmap[i + 2 * S] = (uint8_t)cc;
        cmap[i + 3 * S] = (uint8_t)cd;
        uint32_t m = (u0 != 0) + (u1 != 0) + (u2 != 0) + (u3 != 0)
                   + (u4_ != 0) + (u5 != 0) + (u6 != 0) + (u7 != 0)
                   + (u8 != 0) + (u9 != 0) + (uA != 0) + (uB != 0)
                   + (uC != 0) + (uD != 0) + (uE != 0) + (uF != 0);
        uint32_t excl, tot;
        wscan(m, lane, excl, tot);
        uint32_t p = wcur + excl;
        if (u0)  wseg[p++] = u0;
        if (u1)  wseg[p++] = u1;
        if (u2)  wseg[p++] = u2;
        if (u3)  wseg[p++] = u3;
        if (u4_) wseg[p++] = u4_;
        if (u5)  wseg[p++] = u5;
        if (u6)  wseg[p++] = u6;
        if (u7)  wseg[p++] = u7;
        if (u8)  wseg[p++] = u8;
        if (u9)  wseg[p++] = u9;
        if (uA)  wseg[p++] = uA;
        if (uB)  wseg[p++] = uB;
        if (uC)  wseg[p++] = uC;
        if (uD)  wseg[p++] = uD;
        if (uE)  wseg[p++] = uE;
        if (uF)  wseg[p++] = uF;
        wcur += tot;
    }

    // masked single-quad remainder (wave-uniform loop via __any)
    for (; __any(i < n4); i += S) {
        const bool act = i < n4;
        float4 xa = act ? x4[i] : make_float4(0.f, 0.f, 0.f, 0.f);
        float4 ta = act ? t4[i] : make_float4(0.f, 0.f, 0.f, 0.f);
        uint32_t u0, u1, u2, u3;
        uint32_t ca = quad_u_cls(my, xa, ta, u0, u1, u2, u3);
        if (act) cmap[i] = (uint8_t)ca;
        uint32_t m = (u0 != 0) + (u1 != 0) + (u2 != 0) + (u3 != 0);
        uint32_t excl, tot;
        wscan(m, lane, excl, tot);
        uint32_t p = wcur + excl;
        if (u0) wseg[p++] = u0;
        if (u1) wseg[p++] = u1;
        if (u2) wseg[p++] = u2;
        if (u3) wseg[p++] = u3;
        wcur += tot;
    }

    // n % 4 tail (block 0 only; <4 elems; no cmap — kf reads t for tail)
    if (blockIdx.x == 0) {
        int j = (n4 << 2) + threadIdx.x;
        const bool act = j < n;
        float xx = act ? x[j] : 0.0f;
        float tt = act ? t[j] : 0.0f;
        uint32_t u0 = (tt < 0.0f) ? xform(__float_as_uint(xx)) : 0u;
        if (u0) atomicAdd(&my[u0 >> 21], 1u);
        uint32_t excl, tot;
        wscan(u0 != 0 ? 1u : 0u, lane, excl, tot);
        if (u0) wseg[wcur + excl] = u0;
        wcur += tot;
    }

    if (lane == 0) wvcnt[blockIdx.x * 4 + wid] = wcur;

    __syncthreads();
    // 8-way replicated global hist merge (spreads RMWs across 8x lines)
    uint32_t* hmine = hrep + (size_t)(blockIdx.x & (HREP - 1)) * 2048;
    for (int b2 = threadIdx.x; b2 < 2048; b2 += 256) {
        uint32_t c = lh[b2] + lh[2049 + b2];
        if (c) atomicAdd(&hmine[b2], c);
    }
}

// ---- k2s: redundant prefix1-select + scatter + chunk-sum build (kills scan2a) ----
__global__ __launch_bounds__(256) void k2s(
        const uint32_t* __restrict__ hrep, const int* __restrict__ kptr,
        const uint32_t* __restrict__ cand1, const uint32_t* __restrict__ wvcnt,
        uint32_t* __restrict__ h21, uint32_t* __restrict__ hcoarse,
        SelState* __restrict__ st, int segw) {
    __shared__ uint32_t part[256];
    __shared__ uint32_t bc[2];
    __shared__ uint32_t chist[2 * 1025];   // survivors' chunk ids (2-way repl, +1 pad)
    const int tid = threadIdx.x;

    for (int j = tid; j < 2 * 1025; j += 256) chist[j] = 0;

    // redundant s1: every block reads the 64 KB hrep (L2/L3-hot broadcast)
    uint32_t cnt8[8];
    uint32_t lsum = 0;
#pragma unroll
    for (int j = 0; j < 8; ++j) {
        uint32_t c = 0;
#pragma unroll
        for (int r = 0; r < HREP; ++r) c += hrep[r * 2048 + tid * 8 + j];
        cnt8[j] = c;
        lsum += c;
    }
    part[tid] = lsum;
    __syncthreads();
    for (int off = 1; off < 256; off <<= 1) {   // inclusive suffix sum
        uint32_t add = (tid + off < 256) ? part[tid + off] : 0u;
        __syncthreads();
        part[tid] += add;
        __syncthreads();
    }
    const uint32_t total = part[0];
    int kk = *kptr;
    uint32_t k = (kk > 0) ? (uint32_t)kk : 0u;
    if (k == 0u) {          // keep all negatives (block-uniform early out)
        if (blockIdx.x == 0 && tid == 0) {
            st->done = 1u; st->u_kth = 0xFFFFFFFFu; st->thr_nl = __int_as_float(0x7F800000);
        }
        return;             // h21/hcoarse stay zeroed -> kf uses done path
    }
    if (k > total) {        // drop all negatives
        if (blockIdx.x == 0 && tid == 0) {
            st->done = 1u; st->u_kth = 0u; st->thr_nl = 0.0f;
        }
        return;
    }
    {
        uint32_t A = (tid < 255) ? part[tid + 1] : 0u;  // strictly-above count
#pragma unroll
        for (int j = 7; j >= 0; --j) {
            uint32_t c = cnt8[j];
            if (A < k && k <= A + c) {   // exactly one (thread,bin) per block
                bc[0] = (uint32_t)(tid * 8 + j);
                bc[1] = k - A;
                if (blockIdx.x == 0) {
                    st->done = 0u;
                    st->prefix1 = (uint32_t)(tid * 8 + j);
                    st->k1rem = k - A;
                }
            }
            A += c;
        }
    }
    __syncthreads();
    const uint32_t prefix1 = bc[0];
    uint32_t* mych = &chist[(tid & 1) * 1025];

    // scatter own cand1 segment into h21 + accumulate chunk ids in LDS
    const int lane = tid & 63;
    const int wid  = tid >> 6;
    const int sidx = blockIdx.x * 4 + wid;   // same index k1 wrote: L2-local
    const uint32_t cnt = wvcnt[sidx];
    const uint4* b4 = (const uint4*)(cand1 + (size_t)sidx * (size_t)segw);
    const uint32_t iters = (cnt + 255u) >> 8;
    for (uint32_t it = 0; it < iters; ++it) {
        const uint32_t e0 = it * 256u + (uint32_t)lane * 4u;
        uint4 v = b4[it * 64u + (uint32_t)lane];   // in-bounds: cnt<=256*Q<=segw-4
        if (e0 + 0u < cnt && (v.x >> 21) == prefix1) {
            atomicAdd(&h21[v.x & 0x1FFFFFu], 1u);
            atomicAdd(&mych[(v.x >> 11) & 1023u], 1u);
        }
        if (e0 + 1u < cnt && (v.y >> 21) == prefix1) {
            atomicAdd(&h21[v.y & 0x1FFFFFu], 1u);
            atomicAdd(&mych[(v.y >> 11) & 1023u], 1u);
        }
        if (e0 + 2u < cnt && (v.z >> 21) == prefix1) {
            atomicAdd(&h21[v.z & 0x1FFFFFu], 1u);
            atomicAdd(&mych[(v.z >> 11) & 1023u], 1u);
        }
        if (e0 + 3u < cnt && (v.w >> 21) == prefix1) {
            atomicAdd(&h21[v.w & 0x1FFFFFu], 1u);
            atomicAdd(&mych[(v.w >> 11) & 1023u], 1u);
        }
    }
    __syncthreads();
    // 8-way replicated merge of chunk sums (k1's hrep pattern; very few
    // nonzero bins per block -> few atomics, spread over 8 replicas)
    uint32_t* cmine = hcoarse + (size_t)(blockIdx.x & (HREP - 1)) * 1024;
    for (int b2 = tid; b2 < 1024; b2 += 256) {
        uint32_t c = chist[b2] + chist[1025 + b2];
        if (c) atomicAdd(&cmine[b2], c);
    }
}

// ---------------- final-pass value helpers ----------------
__device__ __forceinline__ float fin1c(float xx, uint32_t cls, uint32_t ukth, float thr) {
    float lp = __logf(1.0f + __expf(-fabsf(xx)));   // HW exp/log
    float v = 0.0f;
    if (cls == 1u) {                    // t = +1
        v = (fmaxf(xx, 0.0f) - xx) + lp;
    } else if (cls == 2u) {             // t = -1
        uint32_t u = xform(__float_as_uint(xx));
        bool keep = u < ukth;
        if (keep && (ukth - u) < GUARD)             // ~0 lanes hit this
            keep = neg_loss_precise(xx, -1.0f) < thr;
        if (keep) v = (fmaxf(-xx, 0.0f) + xx) + lp;
    }
    return v;
}
__device__ __forceinline__ float4 fin_quadc(float4 xv, uint32_t cb, uint32_t ukth, float thr) {
    float4 r;
    r.x = fin1c(xv.x, cb & 3u, ukth, thr);
    r.y = fin1c(xv.y, (cb >> 2) & 3u, ukth, thr);
    r.z = fin1c(xv.z, (cb >> 4) & 3u, ukth, thr);
    r.w = fin1c(xv.w, (cb >> 6) & 3u, ukth, thr);
    return r;
}
__device__ __forceinline__ float fin1t(float xx, float tt, uint32_t ukth, float thr) {
    float lp = __logf(1.0f + __expf(-fabsf(xx)));
    float v = 0.0f;
    if (tt > 0.0f) {
        v = fmaxf(xx, 0.0f) - xx * tt + lp;
    } else if (tt < 0.0f) {
        uint32_t u = xform(__float_as_uint(xx));
        bool keep = u < ukth;
        if (keep && (ukth - u) < GUARD)
            keep = neg_loss_precise(xx, tt) < thr;
        if (keep) v = fmaxf(-xx, 0.0f) - xx * tt + lp;
    }
    return v;
}

// ---------- kf: redundant chunk+bin select (hcoarse + one h21 chunk) + final ----------
__global__ __launch_bounds__(256) void kf(
        const float* __restrict__ x, const float* __restrict__ t,
        const uint8_t* __restrict__ cmap, const uint32_t* __restrict__ h21,
        const uint32_t* __restrict__ hcoarse, const SelState* __restrict__ st,
        float* __restrict__ out, int n) {
    __shared__ uint32_t part[256];
    __shared__ uint32_t bc[4];   // chunk, k2, ukth, thr-bits
    __shared__ uint32_t s_done, s_pref1, s_k1rem, s_ukth, s_thr;
    const int tid = threadIdx.x;
    if (tid == 0) {
        s_done = st->done;  s_pref1 = st->prefix1;  s_k1rem = st->k1rem;
        s_ukth = st->u_kth; s_thr = __float_as_uint(st->thr_nl);
    }
    __syncthreads();

    uint32_t ukth;
    float thr;
    if (s_done) {
        ukth = s_ukth;
        thr = __uint_as_float(s_thr);
    } else {
        // stage 1: chunk select from hcoarse (8 replicas x 1024 bins, L3-hot)
        const uint32_t k = s_k1rem;
        uint32_t c4v[4];
        uint32_t lsum = 0;
#pragma unroll
        for (int j = 0; j < 4; ++j) {
            uint32_t c = 0;
#pragma unroll
            for (int r = 0; r < HREP; ++r) c += hcoarse[r * 1024 + tid * 4 + j];
            c4v[j] = c;
            lsum += c;
        }
        part[tid] = lsum;
        __syncthreads();
        for (int off = 1; off < 256; off <<= 1) {
            uint32_t add = (tid + off < 256) ? part[tid + off] : 0u;
            __syncthreads();
            part[tid] += add;
            __syncthreads();
        }
        uint32_t A = (tid < 255) ? part[tid + 1] : 0u;
#pragma unroll
        for (int j = 3; j >= 0; --j) {
            uint32_t c = c4v[j];
            if (A < k && k <= A + c) { bc[0] = (uint32_t)(tid * 4 + j); bc[1] = k - A; }
            A += c;
        }
        __syncthreads();
        const uint32_t chunk = bc[0];
        const uint32_t k2 = bc[1];
        __syncthreads();

        // stage 2: bin select within the chosen 2048-bin chunk of h21 (8 KB)
        const uint32_t* base = h21 + (size_t)chunk * 2048;
        uint32_t b8[8];
        lsum = 0;
#pragma unroll
        for (int j = 0; j < 8; ++j) { b8[j] = base[tid * 8 + j]; lsum += b8[j]; }
        part[tid] = lsum;
        __syncthreads();
        for (int off = 1; off < 256; off <<= 1) {
            uint32_t add = (tid + off < 256) ? part[tid + off] : 0u;
            __syncthreads();
            part[tid] += add;
            __syncthreads();
        }
        A = (tid < 255) ? part[tid + 1] : 0u;
#pragma unroll
        for (int j = 7; j >= 0; --j) {
            uint32_t c = b8[j];
            if (A < k2 && k2 <= A + c) {
                uint32_t u = (s_pref1 << 21) | (chunk * 2048u + (uint32_t)(tid * 8 + j));
                bc[2] = u;
                bc[3] = __float_as_uint(neg_loss_precise(unxform(u), -1.0f));  // t = -1
            }
            A += c;
        }
        __syncthreads();
        ukth = bc[2];
        thr = __uint_as_float(bc[3]);
    }

    // final output pass
    const float4* x4 = (const float4*)x;
    float4* o4 = (float4*)out;
    const int n4 = n >> 2;
    const int S = gridDim.x * 256;
    int i = blockIdx.x * 256 + tid;
    for (; i + 3 * S < n4; i += 4 * S) {
        float4 xa = x4[i], xb = x4[i + S], xc = x4[i + 2 * S], xd = x4[i + 3 * S];
        uint32_t ca = cmap[i], cb = cmap[i + S], cc = cmap[i + 2 * S], cd = cmap[i + 3 * S];
        o4[i]         = fin_quadc(xa, ca, ukth, thr);
        o4[i + S]     = fin_quadc(xb, cb, ukth, thr);
        o4[i + 2 * S] = fin_quadc(xc, cc, ukth, thr);
        o4[i + 3 * S] = fin_quadc(xd, cd, ukth, thr);
    }
    for (; i < n4; i += S) {
        float4 xa = x4[i];
        uint32_t ca = cmap[i];
        o4[i] = fin_quadc(xa, ca, ukth, thr);
    }
    if (blockIdx.x == 0) {  // n % 4 tail: no cmap — use t directly
        for (int j = (n4 << 2) + tid; j < n; j += 256) {
            out[j] = fin1t(x[j], t[j], ukth, thr);
        }
    }
}

// =====================================================================
extern "C" void kernel_launch(void* const* d_in, const int* in_sizes, int n_in,
                              void* d_out, int out_size, void* d_ws, size_t ws_size,
                              hipStream_t stream) {
    const float* x = (const float*)d_in[0];
    const float* t = (const float*)d_in[1];
    const int* kptr = (const int*)d_in[2];
    float* out = (float*)d_out;
    const int n = in_sizes[0];
    if (n <= 0) return;

    const int n4 = n >> 2;
    int work = (n4 + 255) / 256;
    if (work < 1) work = 1;
    int grid = work < 1024 ? work : 1024;   // 4 blocks/CU
    const int S = grid * 256;
    const int Q = (n4 + S - 1) / S;          // max quads per thread
    const int segw = 256 * Q + 4;            // words per wave segment (16B mult)

    char* ws = (char*)d_ws;
    uint32_t* hrep    = (uint32_t*)(ws + 0);        // 8 x 2048 u32 (64 KB)
    uint32_t* hcoarse = (uint32_t*)(ws + 65536);    // 8 x 1024 u32 (32 KB)
    SelState* st      = (SelState*)(ws + 98304);    // k2s writes before kf reads
    uint32_t* h21     = (uint32_t*)(ws + 98560);    // 2^21 u32 (8 MB; zeroed by k1)
    size_t wvoff = 98560 + ((size_t)1u << 21) * 4u;
    uint32_t* wvcnt   = (uint32_t*)(ws + wvoff);    // 16 KB reserved (always written)
    size_t cmoff = wvoff + 16384;
    uint8_t*  cmap    = (uint8_t*)(ws + cmoff);     // n4 bytes
    size_t c1off = (cmoff + (size_t)n4 + 255) & ~(size_t)255;
    uint32_t* cand1   = (uint32_t*)(ws + c1off);    // nseg*segw u32 (~42 MB)

    // zero hrep + hcoarse + st (96.25 KB) — h21 zeroing lives in k1
    hipMemsetAsync(d_ws, 0, 98560, stream);

    k1_hist<<<grid, 256, 0, stream>>>(x, t, hrep, h21, cand1, wvcnt, cmap, n, segw);
    k2s    <<<grid, 256, 0, stream>>>(hrep, kptr, cand1, wvcnt, h21, hcoarse, st, segw);
    kf     <<<grid, 256, 0, stream>>>(x, t, cmap, h21, hcoarse, st, out, n);
}